// Round 6
// baseline (2367.608 us; speedup 1.0000x reference)
//
#include <hip/hip_runtime.h>
#include <hip/hip_bf16.h>
#include <hip/hip_fp16.h>

// SeaReader forward, MI355X. Round 6: k_rec weight pinning — inline-asm "+v"
// on the 32 uint4 weight scalars defeats load-sinking/remat, forcing true
// register residency of whh across the T-loop. Rest identical to round 5.
// B=4 O=4 L=128 N=8 V=256 H=256; Ls=256; BO=16; BON=128. ws ~103 MB.

typedef unsigned short u16;
typedef unsigned int u32;

__device__ __forceinline__ float bf2f(u16 v) { return __uint_as_float(((u32)v) << 16); }
__device__ __forceinline__ u16 f2b(float f) {
  u32 u = __float_as_uint(f);
  return (u16)((u + 0x7fffu + ((u >> 16) & 1u)) >> 16);  // RNE; finite inputs only
}
__device__ __forceinline__ float ldf(u16 v) { return bf2f(v); }
__device__ __forceinline__ float ldf(float v) { return v; }
__device__ __forceinline__ void stf(u16* p, float v) { *p = f2b(v); }
__device__ __forceinline__ void stf(float* p, float v) { *p = v; }
__device__ __forceinline__ float ldraw(const void* p, size_t i, int isf) {
  return isf ? ((const float*)p)[i] : bf2f(((const u16*)p)[i]);
}
__device__ __forceinline__ __half2 u2h(u32 v) {
  union { u32 u; __half2 h; } c; c.u = v; return c.h;
}

// ---------------- dtype detection ----------------
__global__ void k_detect(const void* __restrict__ stmt, int* __restrict__ flag) {
  if (threadIdx.x == 0 && blockIdx.x == 0) {
    const float* f = (const float*)stmt;
    int sane = 0;
    for (int i = 0; i < 64; ++i) {
      const float a = fabsf(f[i]);
      if (a > 1e-20f && a < 1e6f) sane++;
    }
    *flag = (sane >= 48) ? 1 : 0;
  }
}

// ---------------- convert raw input to bf16 ----------------
__global__ __launch_bounds__(256) void k_cvt(const void* __restrict__ in, u16* __restrict__ out,
                                             int n, const int* __restrict__ flag) {
  const int isf = *flag;
  const int i = blockIdx.x * 256 + threadIdx.x;
  if (i < n) out[i] = f2b(ldraw(in, i, isf));
}

// ---------------- gather stmt = cat(question, answer) -> bf16 ----------------
__global__ __launch_bounds__(256) void k_gather_stmt(const void* __restrict__ statement,
                                                     const void* __restrict__ answer,
                                                     u16* __restrict__ out,
                                                     const int* __restrict__ flag) {
  const int isf = *flag;
  const int idx = blockIdx.x * 256 + threadIdx.x;  // < 16*256*256
  const int v = idx & 255;
  const int s = (idx >> 8) & 255;
  const int bo = idx >> 16;
  float val;
  if (s < 128) val = ldraw(statement, (size_t)(((bo >> 2) * 128) + s) * 256 + v, isf);
  else         val = ldraw(answer, (size_t)((bo * 128) + (s - 128)) * 256 + v, isf);
  out[idx] = f2b(val);
}

// ---- pack whh [768][256] -> fp16 half2 in [k8][768][4] u32 (thread-contiguous uint4) ----
__global__ __launch_bounds__(256) void k_packh(const void* __restrict__ in, u32* __restrict__ out,
                                               int total, const int* __restrict__ flag) {
  const int isf = *flag;
  const int idx = blockIdx.x * 256 + threadIdx.x;  // over 768*128 (row, k2)
  if (idx >= total) return;
  const int r = idx % 768;
  const int k2 = idx / 768;
  const float a = ldraw(in, (size_t)r * 256 + 2 * k2, isf);
  const float b = ldraw(in, (size_t)r * 256 + 2 * k2 + 1, isf);
  const __half2 h2 = __floats2half2_rn(a, b);
  out[(((size_t)(k2 >> 2) * 768) + r) * 4 + (k2 & 3)] = *reinterpret_cast<const u32*>(&h2);
}

// ---------------- recurrent GRU core: xg precomputed; whh pinned in registers ----------------
// One block per sequence, 768 threads = gate-rows. Dual-job (two independent GRUs/launch).
#define LOADW(i) uint4 w##i = wp[(i) * 768];
// Empty asm that "writes" the value: kills rematerialization/load-sinking, forcing
// the allocator to keep all 32 uint4 (=128 VGPRs) live across the T-loop.
#define PINW(i) asm volatile("" : "+v"(w##i.x), "+v"(w##i.y), "+v"(w##i.z), "+v"(w##i.w));
#define STEPW(i)                                                             \
  {                                                                          \
    const uint4 hv = *reinterpret_cast<const uint4*>(&hs_h[(i) * 8]);        \
    a0 = __hfma2(u2h(w##i.x), u2h(hv.x), a0);                                \
    a1 = __hfma2(u2h(w##i.y), u2h(hv.y), a1);                                \
    a2 = __hfma2(u2h(w##i.z), u2h(hv.z), a2);                                \
    a3 = __hfma2(u2h(w##i.w), u2h(hv.w), a3);                                \
  }

__global__ __launch_bounds__(768, 3) void k_rec(
    const u16* __restrict__ xg0, const u32* __restrict__ whh0,
    const u16* __restrict__ bih0, const u16* __restrict__ bhh0,
    u16* __restrict__ oseq0, float* __restrict__ omax0, int nseq0, int T0,
    const u16* __restrict__ xg1, const u32* __restrict__ whh1,
    const u16* __restrict__ bih1, const u16* __restrict__ bhh1,
    u16* __restrict__ oseq1, float* __restrict__ omax1, int T1) {
  const u16 *xg, *bih, *bhh; const u32* whh; u16* oseq; float* omax; int T, seq;
  if ((int)blockIdx.x < nseq0) {
    seq = blockIdx.x; xg = xg0; whh = whh0; bih = bih0; bhh = bhh0;
    oseq = oseq0; omax = omax0; T = T0;
  } else {
    seq = blockIdx.x - nseq0; xg = xg1; whh = whh1; bih = bih1; bhh = bhh1;
    oseq = oseq1; omax = omax1; T = T1;
  }
  __shared__ float hs_f[256];
  __shared__ __align__(16) __half hs_h[256];
  __shared__ float sh[768];
  const int t = threadIdx.x;
  // preload this thread's whh gate-row: 32 uint4 = 128 VGPRs, pinned below
  const uint4* wp = reinterpret_cast<const uint4*>(whh) + t;
  LOADW(0)  LOADW(1)  LOADW(2)  LOADW(3)  LOADW(4)  LOADW(5)  LOADW(6)  LOADW(7)
  LOADW(8)  LOADW(9)  LOADW(10) LOADW(11) LOADW(12) LOADW(13) LOADW(14) LOADW(15)
  LOADW(16) LOADW(17) LOADW(18) LOADW(19) LOADW(20) LOADW(21) LOADW(22) LOADW(23)
  LOADW(24) LOADW(25) LOADW(26) LOADW(27) LOADW(28) LOADW(29) LOADW(30) LOADW(31)
  PINW(0)  PINW(1)  PINW(2)  PINW(3)  PINW(4)  PINW(5)  PINW(6)  PINW(7)
  PINW(8)  PINW(9)  PINW(10) PINW(11) PINW(12) PINW(13) PINW(14) PINW(15)
  PINW(16) PINW(17) PINW(18) PINW(19) PINW(20) PINW(21) PINW(22) PINW(23)
  PINW(24) PINW(25) PINW(26) PINW(27) PINW(28) PINW(29) PINW(30) PINW(31)
  const float bh = bf2f(bhh[t]);
  float bir = 0.f, biz = 0.f, bin = 0.f;
  if (t < 256) {
    bir = bf2f(bih[t]); biz = bf2f(bih[t + 256]); bin = bf2f(bih[t + 512]);
    hs_f[t] = 0.f;
    hs_h[t] = __float2half(0.f);
  }
  float vmax = -3.4e38f;
  const u16* xrow = xg + (size_t)seq * T * 768;
  for (int st = 0; st < T; ++st, xrow += 768) {
    float xr = 0.f, xz = 0.f, xn = 0.f;
    if (t < 256) {  // prefetch this step's x-gates; latency hidden under hh-loop
      xr = bf2f(xrow[t]); xz = bf2f(xrow[t + 256]); xn = bf2f(xrow[t + 512]);
    }
    __syncthreads();  // B1: prev-step h updates visible
    __half2 a0 = __floats2half2_rn(0.f, 0.f), a1 = a0, a2 = a0, a3 = a0;
    STEPW(0)  STEPW(1)  STEPW(2)  STEPW(3)  STEPW(4)  STEPW(5)  STEPW(6)  STEPW(7)
    STEPW(8)  STEPW(9)  STEPW(10) STEPW(11) STEPW(12) STEPW(13) STEPW(14) STEPW(15)
    STEPW(16) STEPW(17) STEPW(18) STEPW(19) STEPW(20) STEPW(21) STEPW(22) STEPW(23)
    STEPW(24) STEPW(25) STEPW(26) STEPW(27) STEPW(28) STEPW(29) STEPW(30) STEPW(31)
    const float ah = (__low2float(a0) + __high2float(a0)) + (__low2float(a1) + __high2float(a1))
                   + (__low2float(a2) + __high2float(a2)) + (__low2float(a3) + __high2float(a3));
    sh[t] = ah + bh;
    __syncthreads();  // B2: sh visible; hs_h reads done
    if (t < 256) {
      const float r = 1.f / (1.f + __expf(-(xr + bir + sh[t])));
      const float z = 1.f / (1.f + __expf(-(xz + biz + sh[t + 256])));
      const float n = tanhf(xn + bin + r * sh[t + 512]);
      const float hnew = (1.f - z) * n + z * hs_f[t];
      hs_f[t] = hnew;
      hs_h[t] = __float2half(hnew);
      if (oseq) oseq[(size_t)(seq * T + st) * 256 + t] = f2b(hnew);
      vmax = fmaxf(vmax, hnew);
    }
    // next B1 fences the h update against next step's reads
  }
  if (omax && t < 256) omax[(size_t)seq * 256 + t] = vmax;
}

// -------- tiled GEMM: C = A * (BT ? B^T : B) (+C), 64x64 tile, fp32 accum --------
template <bool BT, bool CADD, typename TA, typename TB, typename TC>
__global__ __launch_bounds__(256) void k_gemm(
    const TA* __restrict__ Abase, int lda, long strideA, int divA,
    const TB* __restrict__ Bbase, int ldb, long strideB, int divB,
    TC* __restrict__ Cbase, int ldc, long strideC, int K) {
  const int z = blockIdx.z;
  const TA* A = Abase + (size_t)(z / divA) * strideA;
  const TB* Bp = Bbase + (size_t)(z / divB) * strideB;
  TC* C = Cbase + (size_t)z * strideC;
  const int m0 = blockIdx.y << 6, n0 = blockIdx.x << 6;
  __shared__ float As[16][68];
  __shared__ float Bs[16][68];
  const int tid = threadIdx.x;
  const int tx = tid & 15, ty = tid >> 4;
  float acc[4][4] = {};
  for (int k0 = 0; k0 < K; k0 += 16) {
    {
      const int k = tid & 15, m = tid >> 4;
      const TA* ap = A + (size_t)(m0 + m) * lda + (k0 + k);
#pragma unroll
      for (int pp = 0; pp < 4; ++pp) As[k][m + pp * 16] = ldf(ap[(size_t)pp * 16 * lda]);
    }
    if (BT) {
      const int k = tid & 15, n = tid >> 4;
      const TB* bp = Bp + (size_t)(n0 + n) * ldb + (k0 + k);
#pragma unroll
      for (int pp = 0; pp < 4; ++pp) Bs[k][n + pp * 16] = ldf(bp[(size_t)pp * 16 * ldb]);
    } else {
      const int n = tid & 63, k = tid >> 6;
      const TB* bp = Bp + (size_t)(k0 + k) * ldb + (n0 + n);
#pragma unroll
      for (int pp = 0; pp < 4; ++pp) Bs[k + pp * 4][n] = ldf(bp[(size_t)pp * 4 * ldb]);
    }
    __syncthreads();
#pragma unroll
    for (int k = 0; k < 16; ++k) {
      const float4 a = *reinterpret_cast<const float4*>(&As[k][ty << 2]);
      const float4 b = *reinterpret_cast<const float4*>(&Bs[k][tx << 2]);
      acc[0][0] += a.x * b.x; acc[0][1] += a.x * b.y; acc[0][2] += a.x * b.z; acc[0][3] += a.x * b.w;
      acc[1][0] += a.y * b.x; acc[1][1] += a.y * b.y; acc[1][2] += a.y * b.z; acc[1][3] += a.y * b.w;
      acc[2][0] += a.z * b.x; acc[2][1] += a.z * b.y; acc[2][2] += a.z * b.z; acc[2][3] += a.z * b.w;
      acc[3][0] += a.w * b.x; acc[3][1] += a.w * b.y; acc[3][2] += a.w * b.z; acc[3][3] += a.w * b.w;
    }
    __syncthreads();
  }
#pragma unroll
  for (int i = 0; i < 4; ++i) {
    TC* cp = C + (size_t)(m0 + (ty << 2) + i) * ldc + n0 + (tx << 2);
#pragma unroll
    for (int j = 0; j < 4; ++j) {
      float v = acc[i][j];
      if (CADD) v += ldf(cp[j]);
      stf(cp + j, v);
    }
  }
}

// ---------------- row softmax: out = softmax(in) per row ----------------
template <typename TI, typename TO>
__global__ __launch_bounds__(256) void k_softmax_row(const TI* __restrict__ in,
                                                     TO* __restrict__ out, int Lrow) {
  const TI* p = in + (size_t)blockIdx.x * Lrow;
  TO* q = out + (size_t)blockIdx.x * Lrow;
  const int t = threadIdx.x;
  __shared__ float redA[4];
  __shared__ float redB[4];
  float m = -3.4e38f;
  for (int i = t; i < Lrow; i += 256) m = fmaxf(m, ldf(p[i]));
  for (int o = 32; o; o >>= 1) m = fmaxf(m, __shfl_xor(m, o, 64));
  if ((t & 63) == 0) redA[t >> 6] = m;
  __syncthreads();
  m = fmaxf(fmaxf(redA[0], redA[1]), fmaxf(redA[2], redA[3]));
  float s = 0.f;
  for (int i = t; i < Lrow; i += 256) {
    const float e = __expf(ldf(p[i]) - m);
    stf(q + i, e);
    s += e;
  }
  for (int o = 32; o; o >>= 1) s += __shfl_xor(s, o, 64);
  if ((t & 63) == 0) redB[t >> 6] = s;
  __syncthreads();
  s = redB[0] + redB[1] + redB[2] + redB[3];
  const float inv = 1.f / s;
  for (int i = t; i < Lrow; i += 256) stf(q + i, ldf(q[i]) * inv);
}

// -- softmax over s (axis 3) of match[bon][256][128], write transposed [bon][128][256] --
__global__ __launch_bounds__(256) void k_softmax_colT(const float* __restrict__ match,
                                                      u16* __restrict__ qT) {
  const int bon = blockIdx.x, l = blockIdx.y;
  const int t = threadIdx.x;  // s index
  __shared__ float redA[4];
  __shared__ float redB[4];
  const float x = match[((size_t)bon * 256 + t) * 128 + l];
  float m = x;
  for (int o = 32; o; o >>= 1) m = fmaxf(m, __shfl_xor(m, o, 64));
  if ((t & 63) == 0) redA[t >> 6] = m;
  __syncthreads();
  m = fmaxf(fmaxf(redA[0], redA[1]), fmaxf(redA[2], redA[3]));
  const float e = __expf(x - m);
  float s = e;
  for (int o = 32; o; o >>= 1) s += __shfl_xor(s, o, 64);
  if ((t & 63) == 0) redB[t >> 6] = s;
  __syncthreads();
  s = redB[0] + redB[1] + redB[2] + redB[3];
  qT[((size_t)bon * 128 + l) * 256 + t] = f2b(e / s);
}

// ---------------- gate, pool over N, output head, softmax over O ----------------
__global__ __launch_bounds__(256) void k_final(
    const float* __restrict__ s_r, const float* __restrict__ d_r,
    const u16* __restrict__ gw, const u16* __restrict__ gb,
    const u16* __restrict__ ow, const u16* __restrict__ ob,
    void* __restrict__ out, const int* __restrict__ flag) {
  __shared__ float coef[128];
  __shared__ float logits[16];
  const int t = threadIdx.x;
  if (t < 128) {
    float acc = bf2f(gb[0]);
    const float* sp = s_r + (size_t)t * 256;
    const float* dp = d_r + (size_t)t * 256;
    for (int d = 0; d < 256; ++d) acc += bf2f(gw[d]) * sp[d];
    for (int d = 0; d < 256; ++d) acc += bf2f(gw[256 + d]) * dp[d];
    coef[t] = acc;
  }
  __syncthreads();
  if (t < 16) {
    float acc = bf2f(ob[0]);
    for (int d = 0; d < 512; ++d) {
      float mx = -3.4e38f, sm = 0.f;
      for (int n = 0; n < 8; ++n) {
        const int bon = t * 8 + n;
        const float base = (d < 256) ? s_r[(size_t)bon * 256 + d] : d_r[(size_t)bon * 256 + (d - 256)];
        const float v = coef[bon] * base;
        mx = fmaxf(mx, v);
        sm += v;
      }
      acc += bf2f(ow[d]) * mx + bf2f(ow[512 + d]) * (sm * 0.125f);
    }
    logits[t] = acc;
  }
  __syncthreads();
  if (t < 4) {
    const int isf = *flag;
    float m = -3.4e38f;
    for (int o = 0; o < 4; ++o) m = fmaxf(m, logits[t * 4 + o]);
    float e[4], s = 0.f;
    for (int o = 0; o < 4; ++o) { e[o] = __expf(logits[t * 4 + o] - m); s += e[o]; }
    for (int o = 0; o < 4; ++o) {
      const float v = e[o] / s;
      if (isf) ((float*)out)[t * 4 + o] = v;
      else     ((u16*)out)[t * 4 + o] = f2b(v);
    }
  }
}

extern "C" void kernel_launch(void* const* d_in, const int* in_sizes, int n_in,
                              void* d_out, int out_size, void* d_ws, size_t ws_size,
                              hipStream_t stream) {
  (void)in_sizes; (void)n_in; (void)out_size; (void)ws_size;
  const void* statement = d_in[0];
  const void* answer    = d_in[1];
  const void* refs      = d_in[2];
  const void* ctx_wih = d_in[3];
  const void* ctx_whh = d_in[4];
  const void* ctx_bih = d_in[5];
  const void* ctx_bhh = d_in[6];
  const void* sr_wih = d_in[7];
  const void* sr_whh = d_in[8];
  const void* sr_bih = d_in[9];
  const void* sr_bhh = d_in[10];
  const void* dr_wih = d_in[11];
  const void* dr_whh = d_in[12];
  const void* dr_bih = d_in[13];
  const void* dr_bhh = d_in[14];
  const void* gate_w = d_in[15];
  const void* gate_b = d_in[16];
  const void* out_w  = d_in[17];
  const void* out_b  = d_in[18];

  char* ws = (char*)d_ws;
  size_t off = 0;
  auto alloc = [&](size_t bytes) -> void* {
    void* p = ws + off;
    off += (bytes + 255) & ~(size_t)255;
    return p;
  };
  // ---- region A: persistent (~37 MB) ----
  int* FLAG    = (int*)alloc(256);
  u16* CTXWIH  = (u16*)alloc((size_t)768 * 256 * 2);   // bf16 wih (GEMM operand)
  u16* SRWIH   = (u16*)alloc((size_t)768 * 256 * 2);
  u16* DRWIH   = (u16*)alloc((size_t)768 * 512 * 2);
  u32* CTXWHH2 = (u32*)alloc((size_t)128 * 768 * 4);   // fp16 half2, [k8][768][4] u32
  u32* SRWHH2  = (u32*)alloc((size_t)128 * 768 * 4);
  u32* DRWHH2  = (u32*)alloc((size_t)128 * 768 * 4);
  u16* B_CTX_I = (u16*)alloc(768 * 2);
  u16* B_CTX_H = (u16*)alloc(768 * 2);
  u16* B_SR_I  = (u16*)alloc(768 * 2);
  u16* B_SR_H  = (u16*)alloc(768 * 2);
  u16* B_DR_I  = (u16*)alloc(768 * 2);
  u16* B_DR_H  = (u16*)alloc(768 * 2);
  u16* GW = (u16*)alloc(512 * 2);
  u16* GB = (u16*)alloc(2);
  u16* OW = (u16*)alloc(1024 * 2);
  u16* OB = (u16*)alloc(2);
  u16* STMT_H   = (u16*)alloc((size_t)16 * 256 * 256 * 2);   // 2 MB  [bo][s][h]
  u16* DOCS_H   = (u16*)alloc((size_t)128 * 128 * 256 * 2);  // 8 MB  [bon][l][h]
  u16* DOC_READ = (u16*)alloc((size_t)128 * 128 * 256 * 2);  // 8 MB  [bon][l][h]
  u16* ATT      = (u16*)alloc((size_t)128 * 128 * 512 * 2);  // 16 MB [bon][l][2H]
  float* SR_R = (float*)alloc((size_t)128 * 256 * 4);
  float* DR_R = (float*)alloc((size_t)128 * 256 * 4);
  // ---- region B: 66 MB overlay, phase-disjoint lifetimes ----
  const size_t ovl = off;
  u16* REFS_B   = (u16*)(ws + ovl);                           // 8 MB   [phase 1]
  u16* STMT_IN  = (u16*)(ws + ovl + ((size_t)8 << 20));       // 2 MB   [phase 1]
  u16* XG_DOCS  = (u16*)(ws + ovl + ((size_t)16 << 20));      // 24 MB  [phase 1]
  u16* XG_STMT  = (u16*)(ws + ovl + ((size_t)41 << 20));      // 6 MB   [phase 1]
  float* MATCH  = (float*)(ws + ovl);                         // 16 MB  [phase 2]
  u16* P_ROW    = (u16*)(ws + ovl + ((size_t)16 << 20));      // 8 MB   [phase 2]
  u16* MATCH_Q  = (u16*)(ws + ovl + ((size_t)24 << 20));      // 8 MB   [phase 2]
  u16* READ_SUM = (u16*)(ws + ovl + ((size_t)50 << 20));      // 16 MB  [phase 2-3]
  u16* XG_SR    = (u16*)(ws + ovl);                           // 48 MB  [phase 3]
  float* MM     = (float*)(ws + ovl);                         // 64 MB  [phase 4]
  u16* XG_DR    = (u16*)(ws + ovl);                           // 24 MB  [phase 5]

  // 0) dtype detect
  k_detect<<<1, 64, 0, stream>>>(statement, FLAG);

  // 1) conversions / packing
  k_gather_stmt<<<4096, 256, 0, stream>>>(statement, answer, STMT_IN, FLAG);
  k_cvt<<<16384, 256, 0, stream>>>(refs, REFS_B, 4194304, FLAG);
  k_cvt<<<768, 256, 0, stream>>>(ctx_wih, CTXWIH, 196608, FLAG);
  k_cvt<<<768, 256, 0, stream>>>(sr_wih, SRWIH, 196608, FLAG);
  k_cvt<<<1536, 256, 0, stream>>>(dr_wih, DRWIH, 393216, FLAG);
  k_packh<<<384, 256, 0, stream>>>(ctx_whh, CTXWHH2, 98304, FLAG);
  k_packh<<<384, 256, 0, stream>>>(sr_whh, SRWHH2, 98304, FLAG);
  k_packh<<<384, 256, 0, stream>>>(dr_whh, DRWHH2, 98304, FLAG);
  k_cvt<<<3, 256, 0, stream>>>(ctx_bih, B_CTX_I, 768, FLAG);
  k_cvt<<<3, 256, 0, stream>>>(ctx_bhh, B_CTX_H, 768, FLAG);
  k_cvt<<<3, 256, 0, stream>>>(sr_bih, B_SR_I, 768, FLAG);
  k_cvt<<<3, 256, 0, stream>>>(sr_bhh, B_SR_H, 768, FLAG);
  k_cvt<<<3, 256, 0, stream>>>(dr_bih, B_DR_I, 768, FLAG);
  k_cvt<<<3, 256, 0, stream>>>(dr_bhh, B_DR_H, 768, FLAG);
  k_cvt<<<2, 256, 0, stream>>>(gate_w, GW, 512, FLAG);
  k_cvt<<<1, 256, 0, stream>>>(gate_b, GB, 1, FLAG);
  k_cvt<<<4, 256, 0, stream>>>(out_w, OW, 1024, FLAG);
  k_cvt<<<1, 256, 0, stream>>>(out_b, OB, 1, FLAG);

  // 2) ctx input projections: xg = X . wih^T  (M x 768, K=256)
  k_gemm<true, false, u16, u16, u16><<<dim3(12, 64, 1), 256, 0, stream>>>(
      STMT_IN, 256, 0L, 1, CTXWIH, 256, 0L, 1, XG_STMT, 768, 0L, 256);
  k_gemm<true, false, u16, u16, u16><<<dim3(12, 256, 1), 256, 0, stream>>>(
      REFS_B, 256, 0L, 1, CTXWIH, 256, 0L, 1, XG_DOCS, 768, 0L, 256);

  // 3) ctx GRUs, fused: stmt (16 seqs, T=256) + docs (128 seqs, T=128)
  k_rec<<<144, 768, 0, stream>>>(
      XG_STMT, CTXWHH2, B_CTX_I, B_CTX_H, STMT_H, nullptr, 16, 256,
      XG_DOCS, CTXWHH2, B_CTX_I, B_CTX_H, DOCS_H, nullptr, 128);

  // 4) match[bon][s][l] = stmt[bo] . docs[bon]^T  (M=256,N=128,K=256), fp32 out
  k_gemm<true, false, u16, u16, float><<<dim3(2, 4, 128), 256, 0, stream>>>(
      STMT_H, 256, 65536L, 8, DOCS_H, 256, 32768L, 1, MATCH, 128, 32768L, 256);

  // 5) softmaxes from raw logits
  k_softmax_colT<<<dim3(128, 128), 256, 0, stream>>>(MATCH, MATCH_Q);
  k_softmax_row<float, u16><<<32768, 256, 0, stream>>>(MATCH, P_ROW, 128);

  // 6) read_sum[bon][s][h] = P_row . docs  (M=256,N=256,K=128), bf16 out
  k_gemm<false, false, u16, u16, u16><<<dim3(4, 4, 128), 256, 0, stream>>>(
      P_ROW, 128, 32768L, 1, DOCS_H, 256, 32768L, 1, READ_SUM, 256, 65536L, 128);

  // 7) doc_read[bon][l][h] = MATCH_Q . stmt  (M=128,N=256,K=256) — before XG_SR overlay
  k_gemm<false, false, u16, u16, u16><<<dim3(4, 2, 128), 256, 0, stream>>>(
      MATCH_Q, 256, 32768L, 1, STMT_H, 256, 65536L, 8, DOC_READ, 256, 32768L, 256);

  // 8) sr input projection: XG_SR = READ_SUM . sr_wih^T  (M=32768, K=256)
  k_gemm<true, false, u16, u16, u16><<<dim3(12, 512, 1), 256, 0, stream>>>(
      READ_SUM, 256, 0L, 1, SRWIH, 256, 0L, 1, XG_SR, 768, 0L, 256);

  // 9) sr GRU (128 seqs, T=256), max-pooled
  k_rec<<<128, 768, 0, stream>>>(
      XG_SR, SRWHH2, B_SR_I, B_SR_H, nullptr, SR_R, 128, 256,
      nullptr, nullptr, nullptr, nullptr, nullptr, nullptr, 0);

  // 10) mm[bo][nl][m] = docs.docs^T + doc_read.doc_read^T  (M=N=1024,K=256 x2), fp32
  k_gemm<true, false, u16, u16, float><<<dim3(16, 16, 16), 256, 0, stream>>>(
      DOCS_H, 256, 262144L, 1, DOCS_H, 256, 262144L, 1, MM, 1024, 1048576L, 256);
  k_gemm<true, true, u16, u16, float><<<dim3(16, 16, 16), 256, 0, stream>>>(
      DOC_READ, 256, 262144L, 1, DOC_READ, 256, 262144L, 1, MM, 1024, 1048576L, 256);

  // 11) softmax over m, in place (fp32)
  k_softmax_row<float, float><<<16384, 256, 0, stream>>>(MM, MM, 1024);

  // 12) att[bon][l][0:256] = P . docs_flat ; [256:512] = P . doc_read_flat (bf16 out)
  k_gemm<false, false, float, u16, u16><<<dim3(4, 16, 16), 256, 0, stream>>>(
      MM, 1024, 1048576L, 1, DOCS_H, 256, 262144L, 1, ATT, 512, 524288L, 1024);
  k_gemm<false, false, float, u16, u16><<<dim3(4, 16, 16), 256, 0, stream>>>(
      MM, 1024, 1048576L, 1, DOC_READ, 256, 262144L, 1, ATT + 256, 512, 524288L, 1024);

  // 13) dr input projection: XG_DR = ATT . dr_wih^T  (M=16384, K=512) — MM dead
  k_gemm<true, false, u16, u16, u16><<<dim3(12, 256, 1), 256, 0, stream>>>(
      ATT, 512, 0L, 1, DRWIH, 512, 0L, 1, XG_DR, 768, 0L, 512);

  // 14) dr GRU (128 seqs, T=128), max-pooled
  k_rec<<<128, 768, 0, stream>>>(
      XG_DR, DRWHH2, B_DR_I, B_DR_H, nullptr, DR_R, 128, 128,
      nullptr, nullptr, nullptr, nullptr, nullptr, nullptr, 0);

  // 15) gate + pool + head + softmax
  k_final<<<1, 256, 0, stream>>>(SR_R, DR_R, GW, GB, OW, OB, d_out, FLAG);
}

// Round 7
// 1731.965 us; speedup vs baseline: 1.3670x; 1.3670x over previous
//
#include <hip/hip_runtime.h>
#include <hip/hip_bf16.h>
#include <hip/hip_fp16.h>

// SeaReader forward, MI355X. Round 7:
//  (a) k_rec: amdgpu_waves_per_eu(3,3) — allocator stops targeting 2 blocks/CU,
//      lets the 128 pinned weight VGPRs actually stay resident.
//  (b) k_mgemm: bf16 MFMA 16x16x32 GEMM (64x64 tile, fragment-order LDS) replaces
//      the fp32 VALU k_gemm for the whole GEMM stack.
// B=4 O=4 L=128 N=8 V=256 H=256; Ls=256; BO=16; BON=128. ws ~103 MB.

typedef unsigned short u16;
typedef unsigned int u32;
typedef __attribute__((ext_vector_type(8))) short short8;
typedef __attribute__((ext_vector_type(4))) float floatx4;

__device__ __forceinline__ float bf2f(u16 v) { return __uint_as_float(((u32)v) << 16); }
__device__ __forceinline__ u16 f2b(float f) {
  u32 u = __float_as_uint(f);
  return (u16)((u + 0x7fffu + ((u >> 16) & 1u)) >> 16);  // RNE; finite inputs only
}
__device__ __forceinline__ float ldf(u16 v) { return bf2f(v); }
__device__ __forceinline__ float ldf(float v) { return v; }
__device__ __forceinline__ void stf(u16* p, float v) { *p = f2b(v); }
__device__ __forceinline__ void stf(float* p, float v) { *p = v; }
__device__ __forceinline__ float ldraw(const void* p, size_t i, int isf) {
  return isf ? ((const float*)p)[i] : bf2f(((const u16*)p)[i]);
}
__device__ __forceinline__ __half2 u2h(u32 v) {
  union { u32 u; __half2 h; } c; c.u = v; return c.h;
}

// ---------------- dtype detection ----------------
__global__ void k_detect(const void* __restrict__ stmt, int* __restrict__ flag) {
  if (threadIdx.x == 0 && blockIdx.x == 0) {
    const float* f = (const float*)stmt;
    int sane = 0;
    for (int i = 0; i < 64; ++i) {
      const float a = fabsf(f[i]);
      if (a > 1e-20f && a < 1e6f) sane++;
    }
    *flag = (sane >= 48) ? 1 : 0;
  }
}

// ---------------- convert raw input to bf16 ----------------
__global__ __launch_bounds__(256) void k_cvt(const void* __restrict__ in, u16* __restrict__ out,
                                             int n, const int* __restrict__ flag) {
  const int isf = *flag;
  const int i = blockIdx.x * 256 + threadIdx.x;
  if (i < n) out[i] = f2b(ldraw(in, i, isf));
}

// ---------------- gather stmt = cat(question, answer) -> bf16 ----------------
__global__ __launch_bounds__(256) void k_gather_stmt(const void* __restrict__ statement,
                                                     const void* __restrict__ answer,
                                                     u16* __restrict__ out,
                                                     const int* __restrict__ flag) {
  const int isf = *flag;
  const int idx = blockIdx.x * 256 + threadIdx.x;  // < 16*256*256
  const int v = idx & 255;
  const int s = (idx >> 8) & 255;
  const int bo = idx >> 16;
  float val;
  if (s < 128) val = ldraw(statement, (size_t)(((bo >> 2) * 128) + s) * 256 + v, isf);
  else         val = ldraw(answer, (size_t)((bo * 128) + (s - 128)) * 256 + v, isf);
  out[idx] = f2b(val);
}

// ---- pack whh [768][256] -> fp16 half2 in [k8][768][4] u32 (thread-contiguous uint4) ----
__global__ __launch_bounds__(256) void k_packh(const void* __restrict__ in, u32* __restrict__ out,
                                               int total, const int* __restrict__ flag) {
  const int isf = *flag;
  const int idx = blockIdx.x * 256 + threadIdx.x;  // over 768*128 (row, k2)
  if (idx >= total) return;
  const int r = idx % 768;
  const int k2 = idx / 768;
  const float a = ldraw(in, (size_t)r * 256 + 2 * k2, isf);
  const float b = ldraw(in, (size_t)r * 256 + 2 * k2 + 1, isf);
  const __half2 h2 = __floats2half2_rn(a, b);
  out[(((size_t)(k2 >> 2) * 768) + r) * 4 + (k2 & 3)] = *reinterpret_cast<const u32*>(&h2);
}

// ---------------- recurrent GRU core: xg precomputed; whh pinned in registers ----------------
// One block per sequence, 768 threads = gate-rows. Dual-job (two independent GRUs/launch).
#define LOADW(i) uint4 w##i = wp[(i) * 768];
#define PINW(i) asm volatile("" : "+v"(w##i.x), "+v"(w##i.y), "+v"(w##i.z), "+v"(w##i.w));
#define STEPW(i)                                                             \
  {                                                                          \
    const uint4 hv = *reinterpret_cast<const uint4*>(&hs_h[(i) * 8]);        \
    a0 = __hfma2(u2h(w##i.x), u2h(hv.x), a0);                                \
    a1 = __hfma2(u2h(w##i.y), u2h(hv.y), a1);                                \
    a2 = __hfma2(u2h(w##i.z), u2h(hv.z), a2);                                \
    a3 = __hfma2(u2h(w##i.w), u2h(hv.w), a3);                                \
  }

__global__ __attribute__((amdgpu_flat_work_group_size(768, 768), amdgpu_waves_per_eu(3, 3)))
void k_rec(
    const u16* __restrict__ xg0, const u32* __restrict__ whh0,
    const u16* __restrict__ bih0, const u16* __restrict__ bhh0,
    u16* __restrict__ oseq0, float* __restrict__ omax0, int nseq0, int T0,
    const u16* __restrict__ xg1, const u32* __restrict__ whh1,
    const u16* __restrict__ bih1, const u16* __restrict__ bhh1,
    u16* __restrict__ oseq1, float* __restrict__ omax1, int T1) {
  const u16 *xg, *bih, *bhh; const u32* whh; u16* oseq; float* omax; int T, seq;
  if ((int)blockIdx.x < nseq0) {
    seq = blockIdx.x; xg = xg0; whh = whh0; bih = bih0; bhh = bhh0;
    oseq = oseq0; omax = omax0; T = T0;
  } else {
    seq = blockIdx.x - nseq0; xg = xg1; whh = whh1; bih = bih1; bhh = bhh1;
    oseq = oseq1; omax = omax1; T = T1;
  }
  __shared__ float hs_f[256];
  __shared__ __align__(16) __half hs_h[256];
  __shared__ float sh[768];
  const int t = threadIdx.x;
  // preload this thread's whh gate-row: 32 uint4 = 128 VGPRs, pinned
  const uint4* wp = reinterpret_cast<const uint4*>(whh) + t;
  LOADW(0)  LOADW(1)  LOADW(2)  LOADW(3)  LOADW(4)  LOADW(5)  LOADW(6)  LOADW(7)
  LOADW(8)  LOADW(9)  LOADW(10) LOADW(11) LOADW(12) LOADW(13) LOADW(14) LOADW(15)
  LOADW(16) LOADW(17) LOADW(18) LOADW(19) LOADW(20) LOADW(21) LOADW(22) LOADW(23)
  LOADW(24) LOADW(25) LOADW(26) LOADW(27) LOADW(28) LOADW(29) LOADW(30) LOADW(31)
  PINW(0)  PINW(1)  PINW(2)  PINW(3)  PINW(4)  PINW(5)  PINW(6)  PINW(7)
  PINW(8)  PINW(9)  PINW(10) PINW(11) PINW(12) PINW(13) PINW(14) PINW(15)
  PINW(16) PINW(17) PINW(18) PINW(19) PINW(20) PINW(21) PINW(22) PINW(23)
  PINW(24) PINW(25) PINW(26) PINW(27) PINW(28) PINW(29) PINW(30) PINW(31)
  const float bh = bf2f(bhh[t]);
  float bir = 0.f, biz = 0.f, bin = 0.f;
  if (t < 256) {
    bir = bf2f(bih[t]); biz = bf2f(bih[t + 256]); bin = bf2f(bih[t + 512]);
    hs_f[t] = 0.f;
    hs_h[t] = __float2half(0.f);
  }
  float vmax = -3.4e38f;
  const u16* xrow = xg + (size_t)seq * T * 768;
  for (int st = 0; st < T; ++st, xrow += 768) {
    float xr = 0.f, xz = 0.f, xn = 0.f;
    if (t < 256) {  // prefetch this step's x-gates; latency hidden under hh-loop
      xr = bf2f(xrow[t]); xz = bf2f(xrow[t + 256]); xn = bf2f(xrow[t + 512]);
    }
    __syncthreads();  // B1: prev-step h updates visible
    __half2 a0 = __floats2half2_rn(0.f, 0.f), a1 = a0, a2 = a0, a3 = a0;
    STEPW(0)  STEPW(1)  STEPW(2)  STEPW(3)  STEPW(4)  STEPW(5)  STEPW(6)  STEPW(7)
    STEPW(8)  STEPW(9)  STEPW(10) STEPW(11) STEPW(12) STEPW(13) STEPW(14) STEPW(15)
    STEPW(16) STEPW(17) STEPW(18) STEPW(19) STEPW(20) STEPW(21) STEPW(22) STEPW(23)
    STEPW(24) STEPW(25) STEPW(26) STEPW(27) STEPW(28) STEPW(29) STEPW(30) STEPW(31)
    const float ah = (__low2float(a0) + __high2float(a0)) + (__low2float(a1) + __high2float(a1))
                   + (__low2float(a2) + __high2float(a2)) + (__low2float(a3) + __high2float(a3));
    sh[t] = ah + bh;
    __syncthreads();  // B2: sh visible; hs_h reads done
    if (t < 256) {
      const float r = 1.f / (1.f + __expf(-(xr + bir + sh[t])));
      const float z = 1.f / (1.f + __expf(-(xz + biz + sh[t + 256])));
      const float n = tanhf(xn + bin + r * sh[t + 512]);
      const float hnew = (1.f - z) * n + z * hs_f[t];
      hs_f[t] = hnew;
      hs_h[t] = __float2half(hnew);
      if (oseq) oseq[(size_t)(seq * T + st) * 256 + t] = f2b(hnew);
      vmax = fmaxf(vmax, hnew);
    }
    // next B1 fences the h update against next step's reads
  }
  if (omax && t < 256) omax[(size_t)seq * 256 + t] = vmax;
}

// ---------- MFMA bf16 GEMM: C = A * (BT ? B^T : B) (+C), 64x64 tile, 4 waves ----------
// Fragment-order LDS: As[(w*64+lane)*8+j] = A[m0+16w+(lane&15)][k0+8*(lane>>4)+j]
//                     Bs[(nt*64+lane)*8+j] = B[k0+8*(lane>>4)+j][n0+16nt+(lane&15)]
// MFMA layouts per verified notes: A[m=lane&15][k=quad*8+j]; B[k=quad*8+j][n=lane&15];
// D: row=quad*4+reg, col=lane&15.
template <bool BT, bool CADD, typename TA, typename TB, typename TC>
__global__ __launch_bounds__(256) void k_mgemm(
    const TA* __restrict__ Abase, int lda, long strideA, int divA,
    const TB* __restrict__ Bbase, int ldb, long strideB, int divB,
    TC* __restrict__ Cbase, int ldc, long strideC, int K) {
  const int z = blockIdx.z;
  const TA* A = Abase + (size_t)(z / divA) * strideA;
  const TB* Bp = Bbase + (size_t)(z / divB) * strideB;
  TC* C = Cbase + (size_t)z * strideC;
  const int m0 = blockIdx.y << 6, n0 = blockIdx.x << 6;
  __shared__ __align__(16) u16 As[2048];
  __shared__ __align__(16) u16 Bs[2048];
  const int t = threadIdx.x;
  const int lane = t & 63, w = t >> 6;
  floatx4 acc0 = {0.f, 0.f, 0.f, 0.f};
  floatx4 acc1 = {0.f, 0.f, 0.f, 0.f};
  floatx4 acc2 = {0.f, 0.f, 0.f, 0.f};
  floatx4 acc3 = {0.f, 0.f, 0.f, 0.f};
  const int ar = t >> 2;                 // A/BT row (m or n local, 0..63)
  const int ac = (t & 3) << 3;           // k col8
  const int adst = (((ar >> 4) << 6) | (ar & 15) | ((t & 3) << 4)) << 3;
  const int bk = t >> 3;                 // non-BT: k row (0..31)
  const int bn = (t & 7) << 3;           // non-BT: n col8
  for (int k0 = 0; k0 < K; k0 += 32) {
    // stage A[64m][32k] in fragment order
    {
      const TA* ap = A + (size_t)(m0 + ar) * lda + (k0 + ac);
      if constexpr (sizeof(TA) == 2) {
        *reinterpret_cast<uint4*>(&As[adst]) = *reinterpret_cast<const uint4*>(ap);
      } else {
        const float4 f0 = reinterpret_cast<const float4*>(ap)[0];
        const float4 f1 = reinterpret_cast<const float4*>(ap)[1];
        u16* d = &As[adst];
        d[0] = f2b(f0.x); d[1] = f2b(f0.y); d[2] = f2b(f0.z); d[3] = f2b(f0.w);
        d[4] = f2b(f1.x); d[5] = f2b(f1.y); d[6] = f2b(f1.z); d[7] = f2b(f1.w);
      }
    }
    // stage B in fragment order
    if constexpr (BT) {
      const TB* bp = Bp + (size_t)(n0 + ar) * ldb + (k0 + ac);
      *reinterpret_cast<uint4*>(&Bs[adst]) = *reinterpret_cast<const uint4*>(bp);
    } else {
      const TB* bp = Bp + (size_t)(k0 + bk) * ldb + (n0 + bn);
      const uint4 v = *reinterpret_cast<const uint4*>(bp);
      const u16* pv = reinterpret_cast<const u16*>(&v);
#pragma unroll
      for (int j = 0; j < 8; ++j) {
        const int n = bn + j;
        Bs[(((((n >> 4) << 6) | (n & 15) | ((bk >> 3) << 4)) << 3) | (bk & 7))] = pv[j];
      }
    }
    __syncthreads();
    const short8 af = *reinterpret_cast<const short8*>(&As[(w * 64 + lane) << 3]);
    const short8 b0 = *reinterpret_cast<const short8*>(&Bs[(lane) << 3]);
    const short8 b1 = *reinterpret_cast<const short8*>(&Bs[(64 + lane) << 3]);
    const short8 b2 = *reinterpret_cast<const short8*>(&Bs[(128 + lane) << 3]);
    const short8 b3 = *reinterpret_cast<const short8*>(&Bs[(192 + lane) << 3]);
    acc0 = __builtin_amdgcn_mfma_f32_16x16x32_bf16(af, b0, acc0, 0, 0, 0);
    acc1 = __builtin_amdgcn_mfma_f32_16x16x32_bf16(af, b1, acc1, 0, 0, 0);
    acc2 = __builtin_amdgcn_mfma_f32_16x16x32_bf16(af, b2, acc2, 0, 0, 0);
    acc3 = __builtin_amdgcn_mfma_f32_16x16x32_bf16(af, b3, acc3, 0, 0, 0);
    __syncthreads();
  }
  // epilogue: D row = 4*(lane>>4)+i, col = lane&15, per n-tile
  const int q = lane >> 4, cn = lane & 15;
  TC* crow = C + (size_t)(m0 + (w << 4) + (q << 2)) * ldc + n0 + cn;
#pragma unroll
  for (int i = 0; i < 4; ++i) {
    TC* cp = crow + (size_t)i * ldc;
    float v0 = acc0[i], v1 = acc1[i], v2 = acc2[i], v3 = acc3[i];
    if (CADD) { v0 += ldf(cp[0]); v1 += ldf(cp[16]); v2 += ldf(cp[32]); v3 += ldf(cp[48]); }
    stf(cp + 0, v0); stf(cp + 16, v1); stf(cp + 32, v2); stf(cp + 48, v3);
  }
}

// ---------------- row softmax: out = softmax(in) per row ----------------
template <typename TI, typename TO>
__global__ __launch_bounds__(256) void k_softmax_row(const TI* __restrict__ in,
                                                     TO* __restrict__ out, int Lrow) {
  const TI* p = in + (size_t)blockIdx.x * Lrow;
  TO* q = out + (size_t)blockIdx.x * Lrow;
  const int t = threadIdx.x;
  __shared__ float redA[4];
  __shared__ float redB[4];
  float m = -3.4e38f;
  for (int i = t; i < Lrow; i += 256) m = fmaxf(m, ldf(p[i]));
  for (int o = 32; o; o >>= 1) m = fmaxf(m, __shfl_xor(m, o, 64));
  if ((t & 63) == 0) redA[t >> 6] = m;
  __syncthreads();
  m = fmaxf(fmaxf(redA[0], redA[1]), fmaxf(redA[2], redA[3]));
  float s = 0.f;
  for (int i = t; i < Lrow; i += 256) {
    const float e = __expf(ldf(p[i]) - m);
    stf(q + i, e);
    s += e;
  }
  for (int o = 32; o; o >>= 1) s += __shfl_xor(s, o, 64);
  if ((t & 63) == 0) redB[t >> 6] = s;
  __syncthreads();
  s = redB[0] + redB[1] + redB[2] + redB[3];
  const float inv = 1.f / s;
  for (int i = t; i < Lrow; i += 256) stf(q + i, ldf(q[i]) * inv);
}

// -- softmax over s (axis 3) of match[bon][256][128], write transposed [bon][128][256] --
__global__ __launch_bounds__(256) void k_softmax_colT(const float* __restrict__ match,
                                                      u16* __restrict__ qT) {
  const int bon = blockIdx.x, l = blockIdx.y;
  const int t = threadIdx.x;  // s index
  __shared__ float redA[4];
  __shared__ float redB[4];
  const float x = match[((size_t)bon * 256 + t) * 128 + l];
  float m = x;
  for (int o = 32; o; o >>= 1) m = fmaxf(m, __shfl_xor(m, o, 64));
  if ((t & 63) == 0) redA[t >> 6] = m;
  __syncthreads();
  m = fmaxf(fmaxf(redA[0], redA[1]), fmaxf(redA[2], redA[3]));
  const float e = __expf(x - m);
  float s = e;
  for (int o = 32; o; o >>= 1) s += __shfl_xor(s, o, 64);
  if ((t & 63) == 0) redB[t >> 6] = s;
  __syncthreads();
  s = redB[0] + redB[1] + redB[2] + redB[3];
  qT[((size_t)bon * 128 + l) * 256 + t] = f2b(e / s);
}

// ---------------- gate, pool over N, output head, softmax over O ----------------
__global__ __launch_bounds__(256) void k_final(
    const float* __restrict__ s_r, const float* __restrict__ d_r,
    const u16* __restrict__ gw, const u16* __restrict__ gb,
    const u16* __restrict__ ow, const u16* __restrict__ ob,
    void* __restrict__ out, const int* __restrict__ flag) {
  __shared__ float coef[128];
  __shared__ float logits[16];
  const int t = threadIdx.x;
  if (t < 128) {
    float acc = bf2f(gb[0]);
    const float* sp = s_r + (size_t)t * 256;
    const float* dp = d_r + (size_t)t * 256;
    for (int d = 0; d < 256; ++d) acc += bf2f(gw[d]) * sp[d];
    for (int d = 0; d < 256; ++d) acc += bf2f(gw[256 + d]) * dp[d];
    coef[t] = acc;
  }
  __syncthreads();
  if (t < 16) {
    float acc = bf2f(ob[0]);
    for (int d = 0; d < 512; ++d) {
      float mx = -3.4e38f, sm = 0.f;
      for (int n = 0; n < 8; ++n) {
        const int bon = t * 8 + n;
        const float base = (d < 256) ? s_r[(size_t)bon * 256 + d] : d_r[(size_t)bon * 256 + (d - 256)];
        const float v = coef[bon] * base;
        mx = fmaxf(mx, v);
        sm += v;
      }
      acc += bf2f(ow[d]) * mx + bf2f(ow[512 + d]) * (sm * 0.125f);
    }
    logits[t] = acc;
  }
  __syncthreads();
  if (t < 4) {
    const int isf = *flag;
    float m = -3.4e38f;
    for (int o = 0; o < 4; ++o) m = fmaxf(m, logits[t * 4 + o]);
    float e[4], s = 0.f;
    for (int o = 0; o < 4; ++o) { e[o] = __expf(logits[t * 4 + o] - m); s += e[o]; }
    for (int o = 0; o < 4; ++o) {
      const float v = e[o] / s;
      if (isf) ((float*)out)[t * 4 + o] = v;
      else     ((u16*)out)[t * 4 + o] = f2b(v);
    }
  }
}

extern "C" void kernel_launch(void* const* d_in, const int* in_sizes, int n_in,
                              void* d_out, int out_size, void* d_ws, size_t ws_size,
                              hipStream_t stream) {
  (void)in_sizes; (void)n_in; (void)out_size; (void)ws_size;
  const void* statement = d_in[0];
  const void* answer    = d_in[1];
  const void* refs      = d_in[2];
  const void* ctx_wih = d_in[3];
  const void* ctx_whh = d_in[4];
  const void* ctx_bih = d_in[5];
  const void* ctx_bhh = d_in[6];
  const void* sr_wih = d_in[7];
  const void* sr_whh = d_in[8];
  const void* sr_bih = d_in[9];
  const void* sr_bhh = d_in[10];
  const void* dr_wih = d_in[11];
  const void* dr_whh = d_in[12];
  const void* dr_bih = d_in[13];
  const void* dr_bhh = d_in[14];
  const void* gate_w = d_in[15];
  const void* gate_b = d_in[16];
  const void* out_w  = d_in[17];
  const void* out_b  = d_in[18];

  char* ws = (char*)d_ws;
  size_t off = 0;
  auto alloc = [&](size_t bytes) -> void* {
    void* p = ws + off;
    off += (bytes + 255) & ~(size_t)255;
    return p;
  };
  // ---- region A: persistent (~37 MB) ----
  int* FLAG    = (int*)alloc(256);
  u16* CTXWIH  = (u16*)alloc((size_t)768 * 256 * 2);   // bf16 wih (GEMM operand)
  u16* SRWIH   = (u16*)alloc((size_t)768 * 256 * 2);
  u16* DRWIH   = (u16*)alloc((size_t)768 * 512 * 2);
  u32* CTXWHH2 = (u32*)alloc((size_t)128 * 768 * 4);   // fp16 half2, [k8][768][4] u32
  u32* SRWHH2  = (u32*)alloc((size_t)128 * 768 * 4);
  u32* DRWHH2  = (u32*)alloc((size_t)128 * 768 * 4);
  u16* B_CTX_I = (u16*)alloc(768 * 2);
  u16* B_CTX_H = (u16*)alloc(768 * 2);
  u16* B_SR_I  = (u16*)alloc(768 * 2);
  u16* B_SR_H  = (u16*)alloc(768 * 2);
  u16* B_DR_I  = (u16*)alloc(768 * 2);
  u16* B_DR_H  = (u16*)alloc(768 * 2);
  u16* GW = (u16*)alloc(512 * 2);
  u16* GB = (u16*)alloc(2);
  u16* OW = (u16*)alloc(1024 * 2);
  u16* OB = (u16*)alloc(2);
  u16* STMT_H   = (u16*)alloc((size_t)16 * 256 * 256 * 2);   // 2 MB  [bo][s][h]
  u16* DOCS_H   = (u16*)alloc((size_t)128 * 128 * 256 * 2);  // 8 MB  [bon][l][h]
  u16* DOC_READ = (u16*)alloc((size_t)128 * 128 * 256 * 2);  // 8 MB  [bon][l][h]
  u16* ATT      = (u16*)alloc((size_t)128 * 128 * 512 * 2);  // 16 MB [bon][l][2H]
  float* SR_R = (float*)alloc((size_t)128 * 256 * 4);
  float* DR_R = (float*)alloc((size_t)128 * 256 * 4);
  // ---- region B: 66 MB overlay, phase-disjoint lifetimes ----
  const size_t ovl = off;
  u16* REFS_B   = (u16*)(ws + ovl);                           // 8 MB   [phase 1]
  u16* STMT_IN  = (u16*)(ws + ovl + ((size_t)8 << 20));       // 2 MB   [phase 1]
  u16* XG_DOCS  = (u16*)(ws + ovl + ((size_t)16 << 20));      // 24 MB  [phase 1]
  u16* XG_STMT  = (u16*)(ws + ovl + ((size_t)41 << 20));      // 6 MB   [phase 1]
  float* MATCH  = (float*)(ws + ovl);                         // 16 MB  [phase 2]
  u16* P_ROW    = (u16*)(ws + ovl + ((size_t)16 << 20));      // 8 MB   [phase 2]
  u16* MATCH_Q  = (u16*)(ws + ovl + ((size_t)24 << 20));      // 8 MB   [phase 2]
  u16* READ_SUM = (u16*)(ws + ovl + ((size_t)50 << 20));      // 16 MB  [phase 2-3]
  u16* XG_SR    = (u16*)(ws + ovl);                           // 48 MB  [phase 3]
  float* MM     = (float*)(ws + ovl);                         // 64 MB  [phase 4]
  u16* XG_DR    = (u16*)(ws + ovl);                           // 24 MB  [phase 5]

  // 0) dtype detect
  k_detect<<<1, 64, 0, stream>>>(statement, FLAG);

  // 1) conversions / packing
  k_gather_stmt<<<4096, 256, 0, stream>>>(statement, answer, STMT_IN, FLAG);
  k_cvt<<<16384, 256, 0, stream>>>(refs, REFS_B, 4194304, FLAG);
  k_cvt<<<768, 256, 0, stream>>>(ctx_wih, CTXWIH, 196608, FLAG);
  k_cvt<<<768, 256, 0, stream>>>(sr_wih, SRWIH, 196608, FLAG);
  k_cvt<<<1536, 256, 0, stream>>>(dr_wih, DRWIH, 393216, FLAG);
  k_packh<<<384, 256, 0, stream>>>(ctx_whh, CTXWHH2, 98304, FLAG);
  k_packh<<<384, 256, 0, stream>>>(sr_whh, SRWHH2, 98304, FLAG);
  k_packh<<<384, 256, 0, stream>>>(dr_whh, DRWHH2, 98304, FLAG);
  k_cvt<<<3, 256, 0, stream>>>(ctx_bih, B_CTX_I, 768, FLAG);
  k_cvt<<<3, 256, 0, stream>>>(ctx_bhh, B_CTX_H, 768, FLAG);
  k_cvt<<<3, 256, 0, stream>>>(sr_bih, B_SR_I, 768, FLAG);
  k_cvt<<<3, 256, 0, stream>>>(sr_bhh, B_SR_H, 768, FLAG);
  k_cvt<<<3, 256, 0, stream>>>(dr_bih, B_DR_I, 768, FLAG);
  k_cvt<<<3, 256, 0, stream>>>(dr_bhh, B_DR_H, 768, FLAG);
  k_cvt<<<2, 256, 0, stream>>>(gate_w, GW, 512, FLAG);
  k_cvt<<<1, 256, 0, stream>>>(gate_b, GB, 1, FLAG);
  k_cvt<<<4, 256, 0, stream>>>(out_w, OW, 1024, FLAG);
  k_cvt<<<1, 256, 0, stream>>>(out_b, OB, 1, FLAG);

  // 2) ctx input projections: xg = X . wih^T  (M x 768, K=256)
  k_mgemm<true, false, u16, u16, u16><<<dim3(12, 64, 1), 256, 0, stream>>>(
      STMT_IN, 256, 0L, 1, CTXWIH, 256, 0L, 1, XG_STMT, 768, 0L, 256);
  k_mgemm<true, false, u16, u16, u16><<<dim3(12, 256, 1), 256, 0, stream>>>(
      REFS_B, 256, 0L, 1, CTXWIH, 256, 0L, 1, XG_DOCS, 768, 0L, 256);

  // 3) ctx GRUs, fused: stmt (16 seqs, T=256) + docs (128 seqs, T=128)
  k_rec<<<144, 768, 0, stream>>>(
      XG_STMT, CTXWHH2, B_CTX_I, B_CTX_H, STMT_H, nullptr, 16, 256,
      XG_DOCS, CTXWHH2, B_CTX_I, B_CTX_H, DOCS_H, nullptr, 128);

  // 4) match[bon][s][l] = stmt[bo] . docs[bon]^T  (M=256,N=128,K=256), fp32 out
  k_mgemm<true, false, u16, u16, float><<<dim3(2, 4, 128), 256, 0, stream>>>(
      STMT_H, 256, 65536L, 8, DOCS_H, 256, 32768L, 1, MATCH, 128, 32768L, 256);

  // 5) softmaxes from raw logits
  k_softmax_colT<<<dim3(128, 128), 256, 0, stream>>>(MATCH, MATCH_Q);
  k_softmax_row<float, u16><<<32768, 256, 0, stream>>>(MATCH, P_ROW, 128);

  // 6) read_sum[bon][s][h] = P_row . docs  (M=256,N=256,K=128), bf16 out
  k_mgemm<false, false, u16, u16, u16><<<dim3(4, 4, 128), 256, 0, stream>>>(
      P_ROW, 128, 32768L, 1, DOCS_H, 256, 32768L, 1, READ_SUM, 256, 65536L, 128);

  // 7) doc_read[bon][l][h] = MATCH_Q . stmt  (M=128,N=256,K=256) — before XG_SR overlay
  k_mgemm<false, false, u16, u16, u16><<<dim3(4, 2, 128), 256, 0, stream>>>(
      MATCH_Q, 256, 32768L, 1, STMT_H, 256, 65536L, 8, DOC_READ, 256, 32768L, 256);

  // 8) sr input projection: XG_SR = READ_SUM . sr_wih^T  (M=32768, K=256)
  k_mgemm<true, false, u16, u16, u16><<<dim3(12, 512, 1), 256, 0, stream>>>(
      READ_SUM, 256, 0L, 1, SRWIH, 256, 0L, 1, XG_SR, 768, 0L, 256);

  // 9) sr GRU (128 seqs, T=256), max-pooled
  k_rec<<<128, 768, 0, stream>>>(
      XG_SR, SRWHH2, B_SR_I, B_SR_H, nullptr, SR_R, 128, 256,
      nullptr, nullptr, nullptr, nullptr, nullptr, nullptr, 0);

  // 10) mm[bo][nl][m] = docs.docs^T + doc_read.doc_read^T  (M=N=1024,K=256 x2), fp32
  k_mgemm<true, false, u16, u16, float><<<dim3(16, 16, 16), 256, 0, stream>>>(
      DOCS_H, 256, 262144L, 1, DOCS_H, 256, 262144L, 1, MM, 1024, 1048576L, 256);
  k_mgemm<true, true, u16, u16, float><<<dim3(16, 16, 16), 256, 0, stream>>>(
      DOC_READ, 256, 262144L, 1, DOC_READ, 256, 262144L, 1, MM, 1024, 1048576L, 256);

  // 11) softmax over m, in place (fp32)
  k_softmax_row<float, float><<<16384, 256, 0, stream>>>(MM, MM, 1024);

  // 12) att[bon][l][0:256] = P . docs_flat ; [256:512] = P . doc_read_flat (bf16 out)
  k_mgemm<false, false, float, u16, u16><<<dim3(4, 16, 16), 256, 0, stream>>>(
      MM, 1024, 1048576L, 1, DOCS_H, 256, 262144L, 1, ATT, 512, 524288L, 1024);
  k_mgemm<false, false, float, u16, u16><<<dim3(4, 16, 16), 256, 0, stream>>>(
      MM, 1024, 1048576L, 1, DOC_READ, 256, 262144L, 1, ATT + 256, 512, 524288L, 1024);

  // 13) dr input projection: XG_DR = ATT . dr_wih^T  (M=16384, K=512) — MM dead
  k_mgemm<true, false, u16, u16, u16><<<dim3(12, 256, 1), 256, 0, stream>>>(
      ATT, 512, 0L, 1, DRWIH, 512, 0L, 1, XG_DR, 768, 0L, 512);

  // 14) dr GRU (128 seqs, T=128), max-pooled
  k_rec<<<128, 768, 0, stream>>>(
      XG_DR, DRWHH2, B_DR_I, B_DR_H, nullptr, DR_R, 128, 128,
      nullptr, nullptr, nullptr, nullptr, nullptr, nullptr, 0);

  // 15) gate + pool + head + softmax
  k_final<<<1, 256, 0, stream>>>(SR_R, DR_R, GW, GB, OW, OB, d_out, FLAG);
}

// Round 8
// 1711.451 us; speedup vs baseline: 1.3834x; 1.0120x over previous
//
#include <hip/hip_runtime.h>
#include <hip/hip_bf16.h>
#include <hip/hip_fp16.h>

// SeaReader forward, MI355X. Round 8: k_rec occupancy forcing — static 82KB LDS
// arena caps the CU at 1 block (3 waves/SIMD), raising the register allocator's
// VGPR budget to ~170 so the 128 pinned whh VGPRs can stay resident instead of
// being spilled/re-streamed (per-CU L1-bound at 393KB/step in rounds 4-7).
// Rest identical to round 7 (MFMA GEMM stack + pinned-weight k_rec).
// B=4 O=4 L=128 N=8 V=256 H=256; Ls=256; BO=16; BON=128. ws ~103 MB.

typedef unsigned short u16;
typedef unsigned int u32;
typedef __attribute__((ext_vector_type(8))) short short8;
typedef __attribute__((ext_vector_type(4))) float floatx4;

__device__ __forceinline__ float bf2f(u16 v) { return __uint_as_float(((u32)v) << 16); }
__device__ __forceinline__ u16 f2b(float f) {
  u32 u = __float_as_uint(f);
  return (u16)((u + 0x7fffu + ((u >> 16) & 1u)) >> 16);  // RNE; finite inputs only
}
__device__ __forceinline__ float ldf(u16 v) { return bf2f(v); }
__device__ __forceinline__ float ldf(float v) { return v; }
__device__ __forceinline__ void stf(u16* p, float v) { *p = f2b(v); }
__device__ __forceinline__ void stf(float* p, float v) { *p = v; }
__device__ __forceinline__ float ldraw(const void* p, size_t i, int isf) {
  return isf ? ((const float*)p)[i] : bf2f(((const u16*)p)[i]);
}
__device__ __forceinline__ __half2 u2h(u32 v) {
  union { u32 u; __half2 h; } c; c.u = v; return c.h;
}

// ---------------- dtype detection ----------------
__global__ void k_detect(const void* __restrict__ stmt, int* __restrict__ flag) {
  if (threadIdx.x == 0 && blockIdx.x == 0) {
    const float* f = (const float*)stmt;
    int sane = 0;
    for (int i = 0; i < 64; ++i) {
      const float a = fabsf(f[i]);
      if (a > 1e-20f && a < 1e6f) sane++;
    }
    *flag = (sane >= 48) ? 1 : 0;
  }
}

// ---------------- convert raw input to bf16 ----------------
__global__ __launch_bounds__(256) void k_cvt(const void* __restrict__ in, u16* __restrict__ out,
                                             int n, const int* __restrict__ flag) {
  const int isf = *flag;
  const int i = blockIdx.x * 256 + threadIdx.x;
  if (i < n) out[i] = f2b(ldraw(in, i, isf));
}

// ---------------- gather stmt = cat(question, answer) -> bf16 ----------------
__global__ __launch_bounds__(256) void k_gather_stmt(const void* __restrict__ statement,
                                                     const void* __restrict__ answer,
                                                     u16* __restrict__ out,
                                                     const int* __restrict__ flag) {
  const int isf = *flag;
  const int idx = blockIdx.x * 256 + threadIdx.x;  // < 16*256*256
  const int v = idx & 255;
  const int s = (idx >> 8) & 255;
  const int bo = idx >> 16;
  float val;
  if (s < 128) val = ldraw(statement, (size_t)(((bo >> 2) * 128) + s) * 256 + v, isf);
  else         val = ldraw(answer, (size_t)((bo * 128) + (s - 128)) * 256 + v, isf);
  out[idx] = f2b(val);
}

// ---- pack whh [768][256] -> fp16 half2 in [k8][768][4] u32 (thread-contiguous uint4) ----
__global__ __launch_bounds__(256) void k_packh(const void* __restrict__ in, u32* __restrict__ out,
                                               int total, const int* __restrict__ flag) {
  const int isf = *flag;
  const int idx = blockIdx.x * 256 + threadIdx.x;  // over 768*128 (row, k2)
  if (idx >= total) return;
  const int r = idx % 768;
  const int k2 = idx / 768;
  const float a = ldraw(in, (size_t)r * 256 + 2 * k2, isf);
  const float b = ldraw(in, (size_t)r * 256 + 2 * k2 + 1, isf);
  const __half2 h2 = __floats2half2_rn(a, b);
  out[(((size_t)(k2 >> 2) * 768) + r) * 4 + (k2 & 3)] = *reinterpret_cast<const u32*>(&h2);
}

// ---------------- recurrent GRU core: xg precomputed; whh pinned in registers ----------------
// One block per sequence, 768 threads = gate-rows. Dual-job (two independent GRUs/launch).
// Static 82KB LDS arena -> 1 block/CU (3 waves/SIMD) -> VGPR budget ~170 -> the
// 32 pinned uint4 (128 VGPRs) of whh can stay live across the whole T-loop.
#define LOADW(i) uint4 w##i = wp[(i) * 768];
#define PINW(i) asm volatile("" : "+v"(w##i.x), "+v"(w##i.y), "+v"(w##i.z), "+v"(w##i.w));
#define STEPW(i)                                                             \
  {                                                                          \
    const uint4 hv = *reinterpret_cast<const uint4*>(&hs_h[(i) * 8]);        \
    a0 = __hfma2(u2h(w##i.x), u2h(hv.x), a0);                                \
    a1 = __hfma2(u2h(w##i.y), u2h(hv.y), a1);                                \
    a2 = __hfma2(u2h(w##i.z), u2h(hv.z), a2);                                \
    a3 = __hfma2(u2h(w##i.w), u2h(hv.w), a3);                                \
  }

__global__ __attribute__((amdgpu_flat_work_group_size(768, 768), amdgpu_waves_per_eu(3, 3)))
void k_rec(
    const u16* __restrict__ xg0, const u32* __restrict__ whh0,
    const u16* __restrict__ bih0, const u16* __restrict__ bhh0,
    u16* __restrict__ oseq0, float* __restrict__ omax0, int nseq0, int T0,
    const u16* __restrict__ xg1, const u32* __restrict__ whh1,
    const u16* __restrict__ bih1, const u16* __restrict__ bhh1,
    u16* __restrict__ oseq1, float* __restrict__ omax1, int T1) {
  // 82,176 B static LDS: 2 blocks would need 164,352 > 163,840 -> 1 block/CU.
  __shared__ __align__(16) char smem[82176];
  float* hs_f = reinterpret_cast<float*>(smem);                    // 256 f32
  __half* hs_h = reinterpret_cast<__half*>(smem + 1024);           // 256 f16
  float* sh = reinterpret_cast<float*>(smem + 2048);               // 768 f32
  const u16 *xg, *bih, *bhh; const u32* whh; u16* oseq; float* omax; int T, seq;
  if ((int)blockIdx.x < nseq0) {
    seq = blockIdx.x; xg = xg0; whh = whh0; bih = bih0; bhh = bhh0;
    oseq = oseq0; omax = omax0; T = T0;
  } else {
    seq = blockIdx.x - nseq0; xg = xg1; whh = whh1; bih = bih1; bhh = bhh1;
    oseq = oseq1; omax = omax1; T = T1;
  }
  const int t = threadIdx.x;
  // preload this thread's whh gate-row: 32 uint4 = 128 VGPRs, pinned
  const uint4* wp = reinterpret_cast<const uint4*>(whh) + t;
  LOADW(0)  LOADW(1)  LOADW(2)  LOADW(3)  LOADW(4)  LOADW(5)  LOADW(6)  LOADW(7)
  LOADW(8)  LOADW(9)  LOADW(10) LOADW(11) LOADW(12) LOADW(13) LOADW(14) LOADW(15)
  LOADW(16) LOADW(17) LOADW(18) LOADW(19) LOADW(20) LOADW(21) LOADW(22) LOADW(23)
  LOADW(24) LOADW(25) LOADW(26) LOADW(27) LOADW(28) LOADW(29) LOADW(30) LOADW(31)
  PINW(0)  PINW(1)  PINW(2)  PINW(3)  PINW(4)  PINW(5)  PINW(6)  PINW(7)
  PINW(8)  PINW(9)  PINW(10) PINW(11) PINW(12) PINW(13) PINW(14) PINW(15)
  PINW(16) PINW(17) PINW(18) PINW(19) PINW(20) PINW(21) PINW(22) PINW(23)
  PINW(24) PINW(25) PINW(26) PINW(27) PINW(28) PINW(29) PINW(30) PINW(31)
  const float bh = bf2f(bhh[t]);
  float bir = 0.f, biz = 0.f, bin = 0.f;
  if (t < 256) {
    bir = bf2f(bih[t]); biz = bf2f(bih[t + 256]); bin = bf2f(bih[t + 512]);
    hs_f[t] = 0.f;
    hs_h[t] = __float2half(0.f);
  }
  float vmax = -3.4e38f;
  const u16* xrow = xg + (size_t)seq * T * 768;
  for (int st = 0; st < T; ++st, xrow += 768) {
    float xr = 0.f, xz = 0.f, xn = 0.f;
    if (t < 256) {  // prefetch this step's x-gates; latency hidden under hh-loop
      xr = bf2f(xrow[t]); xz = bf2f(xrow[t + 256]); xn = bf2f(xrow[t + 512]);
    }
    __syncthreads();  // B1: prev-step h updates visible
    __half2 a0 = __floats2half2_rn(0.f, 0.f), a1 = a0, a2 = a0, a3 = a0;
    STEPW(0)  STEPW(1)  STEPW(2)  STEPW(3)  STEPW(4)  STEPW(5)  STEPW(6)  STEPW(7)
    STEPW(8)  STEPW(9)  STEPW(10) STEPW(11) STEPW(12) STEPW(13) STEPW(14) STEPW(15)
    STEPW(16) STEPW(17) STEPW(18) STEPW(19) STEPW(20) STEPW(21) STEPW(22) STEPW(23)
    STEPW(24) STEPW(25) STEPW(26) STEPW(27) STEPW(28) STEPW(29) STEPW(30) STEPW(31)
    const float ah = (__low2float(a0) + __high2float(a0)) + (__low2float(a1) + __high2float(a1))
                   + (__low2float(a2) + __high2float(a2)) + (__low2float(a3) + __high2float(a3));
    sh[t] = ah + bh;
    __syncthreads();  // B2: sh visible; hs_h reads done
    if (t < 256) {
      const float r = 1.f / (1.f + __expf(-(xr + bir + sh[t])));
      const float z = 1.f / (1.f + __expf(-(xz + biz + sh[t + 256])));
      const float n = tanhf(xn + bin + r * sh[t + 512]);
      const float hnew = (1.f - z) * n + z * hs_f[t];
      hs_f[t] = hnew;
      hs_h[t] = __float2half(hnew);
      if (oseq) oseq[(size_t)(seq * T + st) * 256 + t] = f2b(hnew);
      vmax = fmaxf(vmax, hnew);
    }
    // next B1 fences the h update against next step's reads
  }
  if (omax && t < 256) omax[(size_t)seq * 256 + t] = vmax;
}

// ---------- MFMA bf16 GEMM: C = A * (BT ? B^T : B) (+C), 64x64 tile, 4 waves ----------
// Fragment-order LDS: As[(w*64+lane)*8+j] = A[m0+16w+(lane&15)][k0+8*(lane>>4)+j]
//                     Bs[(nt*64+lane)*8+j] = B[k0+8*(lane>>4)+j][n0+16nt+(lane&15)]
// MFMA layouts per verified notes: A[m=lane&15][k=quad*8+j]; B[k=quad*8+j][n=lane&15];
// D: row=quad*4+reg, col=lane&15.
template <bool BT, bool CADD, typename TA, typename TB, typename TC>
__global__ __launch_bounds__(256) void k_mgemm(
    const TA* __restrict__ Abase, int lda, long strideA, int divA,
    const TB* __restrict__ Bbase, int ldb, long strideB, int divB,
    TC* __restrict__ Cbase, int ldc, long strideC, int K) {
  const int z = blockIdx.z;
  const TA* A = Abase + (size_t)(z / divA) * strideA;
  const TB* Bp = Bbase + (size_t)(z / divB) * strideB;
  TC* C = Cbase + (size_t)z * strideC;
  const int m0 = blockIdx.y << 6, n0 = blockIdx.x << 6;
  __shared__ __align__(16) u16 As[2048];
  __shared__ __align__(16) u16 Bs[2048];
  const int t = threadIdx.x;
  const int lane = t & 63, w = t >> 6;
  floatx4 acc0 = {0.f, 0.f, 0.f, 0.f};
  floatx4 acc1 = {0.f, 0.f, 0.f, 0.f};
  floatx4 acc2 = {0.f, 0.f, 0.f, 0.f};
  floatx4 acc3 = {0.f, 0.f, 0.f, 0.f};
  const int ar = t >> 2;                 // A/BT row (m or n local, 0..63)
  const int ac = (t & 3) << 3;           // k col8
  const int adst = (((ar >> 4) << 6) | (ar & 15) | ((t & 3) << 4)) << 3;
  const int bk = t >> 3;                 // non-BT: k row (0..31)
  const int bn = (t & 7) << 3;           // non-BT: n col8
  for (int k0 = 0; k0 < K; k0 += 32) {
    // stage A[64m][32k] in fragment order
    {
      const TA* ap = A + (size_t)(m0 + ar) * lda + (k0 + ac);
      if constexpr (sizeof(TA) == 2) {
        *reinterpret_cast<uint4*>(&As[adst]) = *reinterpret_cast<const uint4*>(ap);
      } else {
        const float4 f0 = reinterpret_cast<const float4*>(ap)[0];
        const float4 f1 = reinterpret_cast<const float4*>(ap)[1];
        u16* d = &As[adst];
        d[0] = f2b(f0.x); d[1] = f2b(f0.y); d[2] = f2b(f0.z); d[3] = f2b(f0.w);
        d[4] = f2b(f1.x); d[5] = f2b(f1.y); d[6] = f2b(f1.z); d[7] = f2b(f1.w);
      }
    }
    // stage B in fragment order
    if constexpr (BT) {
      const TB* bp = Bp + (size_t)(n0 + ar) * ldb + (k0 + ac);
      *reinterpret_cast<uint4*>(&Bs[adst]) = *reinterpret_cast<const uint4*>(bp);
    } else {
      const TB* bp = Bp + (size_t)(k0 + bk) * ldb + (n0 + bn);
      const uint4 v = *reinterpret_cast<const uint4*>(bp);
      const u16* pv = reinterpret_cast<const u16*>(&v);
#pragma unroll
      for (int j = 0; j < 8; ++j) {
        const int n = bn + j;
        Bs[(((((n >> 4) << 6) | (n & 15) | ((bk >> 3) << 4)) << 3) | (bk & 7))] = pv[j];
      }
    }
    __syncthreads();
    const short8 af = *reinterpret_cast<const short8*>(&As[(w * 64 + lane) << 3]);
    const short8 b0 = *reinterpret_cast<const short8*>(&Bs[(lane) << 3]);
    const short8 b1 = *reinterpret_cast<const short8*>(&Bs[(64 + lane) << 3]);
    const short8 b2 = *reinterpret_cast<const short8*>(&Bs[(128 + lane) << 3]);
    const short8 b3 = *reinterpret_cast<const short8*>(&Bs[(192 + lane) << 3]);
    acc0 = __builtin_amdgcn_mfma_f32_16x16x32_bf16(af, b0, acc0, 0, 0, 0);
    acc1 = __builtin_amdgcn_mfma_f32_16x16x32_bf16(af, b1, acc1, 0, 0, 0);
    acc2 = __builtin_amdgcn_mfma_f32_16x16x32_bf16(af, b2, acc2, 0, 0, 0);
    acc3 = __builtin_amdgcn_mfma_f32_16x16x32_bf16(af, b3, acc3, 0, 0, 0);
    __syncthreads();
  }
  // epilogue: D row = 4*(lane>>4)+i, col = lane&15, per n-tile
  const int q = lane >> 4, cn = lane & 15;
  TC* crow = C + (size_t)(m0 + (w << 4) + (q << 2)) * ldc + n0 + cn;
#pragma unroll
  for (int i = 0; i < 4; ++i) {
    TC* cp = crow + (size_t)i * ldc;
    float v0 = acc0[i], v1 = acc1[i], v2 = acc2[i], v3 = acc3[i];
    if (CADD) { v0 += ldf(cp[0]); v1 += ldf(cp[16]); v2 += ldf(cp[32]); v3 += ldf(cp[48]); }
    stf(cp + 0, v0); stf(cp + 16, v1); stf(cp + 32, v2); stf(cp + 48, v3);
  }
}

// ---------------- row softmax: out = softmax(in) per row ----------------
template <typename TI, typename TO>
__global__ __launch_bounds__(256) void k_softmax_row(const TI* __restrict__ in,
                                                     TO* __restrict__ out, int Lrow) {
  const TI* p = in + (size_t)blockIdx.x * Lrow;
  TO* q = out + (size_t)blockIdx.x * Lrow;
  const int t = threadIdx.x;
  __shared__ float redA[4];
  __shared__ float redB[4];
  float m = -3.4e38f;
  for (int i = t; i < Lrow; i += 256) m = fmaxf(m, ldf(p[i]));
  for (int o = 32; o; o >>= 1) m = fmaxf(m, __shfl_xor(m, o, 64));
  if ((t & 63) == 0) redA[t >> 6] = m;
  __syncthreads();
  m = fmaxf(fmaxf(redA[0], redA[1]), fmaxf(redA[2], redA[3]));
  float s = 0.f;
  for (int i = t; i < Lrow; i += 256) {
    const float e = __expf(ldf(p[i]) - m);
    stf(q + i, e);
    s += e;
  }
  for (int o = 32; o; o >>= 1) s += __shfl_xor(s, o, 64);
  if ((t & 63) == 0) redB[t >> 6] = s;
  __syncthreads();
  s = redB[0] + redB[1] + redB[2] + redB[3];
  const float inv = 1.f / s;
  for (int i = t; i < Lrow; i += 256) stf(q + i, ldf(q[i]) * inv);
}

// -- softmax over s (axis 3) of match[bon][256][128], write transposed [bon][128][256] --
__global__ __launch_bounds__(256) void k_softmax_colT(const float* __restrict__ match,
                                                      u16* __restrict__ qT) {
  const int bon = blockIdx.x, l = blockIdx.y;
  const int t = threadIdx.x;  // s index
  __shared__ float redA[4];
  __shared__ float redB[4];
  const float x = match[((size_t)bon * 256 + t) * 128 + l];
  float m = x;
  for (int o = 32; o; o >>= 1) m = fmaxf(m, __shfl_xor(m, o, 64));
  if ((t & 63) == 0) redA[t >> 6] = m;
  __syncthreads();
  m = fmaxf(fmaxf(redA[0], redA[1]), fmaxf(redA[2], redA[3]));
  const float e = __expf(x - m);
  float s = e;
  for (int o = 32; o; o >>= 1) s += __shfl_xor(s, o, 64);
  if ((t & 63) == 0) redB[t >> 6] = s;
  __syncthreads();
  s = redB[0] + redB[1] + redB[2] + redB[3];
  qT[((size_t)bon * 128 + l) * 256 + t] = f2b(e / s);
}

// ---------------- gate, pool over N, output head, softmax over O ----------------
__global__ __launch_bounds__(256) void k_final(
    const float* __restrict__ s_r, const float* __restrict__ d_r,
    const u16* __restrict__ gw, const u16* __restrict__ gb,
    const u16* __restrict__ ow, const u16* __restrict__ ob,
    void* __restrict__ out, const int* __restrict__ flag) {
  __shared__ float coef[128];
  __shared__ float logits[16];
  const int t = threadIdx.x;
  if (t < 128) {
    float acc = bf2f(gb[0]);
    const float* sp = s_r + (size_t)t * 256;
    const float* dp = d_r + (size_t)t * 256;
    for (int d = 0; d < 256; ++d) acc += bf2f(gw[d]) * sp[d];
    for (int d = 0; d < 256; ++d) acc += bf2f(gw[256 + d]) * dp[d];
    coef[t] = acc;
  }
  __syncthreads();
  if (t < 16) {
    float acc = bf2f(ob[0]);
    for (int d = 0; d < 512; ++d) {
      float mx = -3.4e38f, sm = 0.f;
      for (int n = 0; n < 8; ++n) {
        const int bon = t * 8 + n;
        const float base = (d < 256) ? s_r[(size_t)bon * 256 + d] : d_r[(size_t)bon * 256 + (d - 256)];
        const float v = coef[bon] * base;
        mx = fmaxf(mx, v);
        sm += v;
      }
      acc += bf2f(ow[d]) * mx + bf2f(ow[512 + d]) * (sm * 0.125f);
    }
    logits[t] = acc;
  }
  __syncthreads();
  if (t < 4) {
    const int isf = *flag;
    float m = -3.4e38f;
    for (int o = 0; o < 4; ++o) m = fmaxf(m, logits[t * 4 + o]);
    float e[4], s = 0.f;
    for (int o = 0; o < 4; ++o) { e[o] = __expf(logits[t * 4 + o] - m); s += e[o]; }
    for (int o = 0; o < 4; ++o) {
      const float v = e[o] / s;
      if (isf) ((float*)out)[t * 4 + o] = v;
      else     ((u16*)out)[t * 4 + o] = f2b(v);
    }
  }
}

extern "C" void kernel_launch(void* const* d_in, const int* in_sizes, int n_in,
                              void* d_out, int out_size, void* d_ws, size_t ws_size,
                              hipStream_t stream) {
  (void)in_sizes; (void)n_in; (void)out_size; (void)ws_size;
  const void* statement = d_in[0];
  const void* answer    = d_in[1];
  const void* refs      = d_in[2];
  const void* ctx_wih = d_in[3];
  const void* ctx_whh = d_in[4];
  const void* ctx_bih = d_in[5];
  const void* ctx_bhh = d_in[6];
  const void* sr_wih = d_in[7];
  const void* sr_whh = d_in[8];
  const void* sr_bih = d_in[9];
  const void* sr_bhh = d_in[10];
  const void* dr_wih = d_in[11];
  const void* dr_whh = d_in[12];
  const void* dr_bih = d_in[13];
  const void* dr_bhh = d_in[14];
  const void* gate_w = d_in[15];
  const void* gate_b = d_in[16];
  const void* out_w  = d_in[17];
  const void* out_b  = d_in[18];

  char* ws = (char*)d_ws;
  size_t off = 0;
  auto alloc = [&](size_t bytes) -> void* {
    void* p = ws + off;
    off += (bytes + 255) & ~(size_t)255;
    return p;
  };
  // ---- region A: persistent (~37 MB) ----
  int* FLAG    = (int*)alloc(256);
  u16* CTXWIH  = (u16*)alloc((size_t)768 * 256 * 2);   // bf16 wih (GEMM operand)
  u16* SRWIH   = (u16*)alloc((size_t)768 * 256 * 2);
  u16* DRWIH   = (u16*)alloc((size_t)768 * 512 * 2);
  u32* CTXWHH2 = (u32*)alloc((size_t)128 * 768 * 4);   // fp16 half2, [k8][768][4] u32
  u32* SRWHH2  = (u32*)alloc((size_t)128 * 768 * 4);
  u32* DRWHH2  = (u32*)alloc((size_t)128 * 768 * 4);
  u16* B_CTX_I = (u16*)alloc(768 * 2);
  u16* B_CTX_H = (u16*)alloc(768 * 2);
  u16* B_SR_I  = (u16*)alloc(768 * 2);
  u16* B_SR_H  = (u16*)alloc(768 * 2);
  u16* B_DR_I  = (u16*)alloc(768 * 2);
  u16* B_DR_H  = (u16*)alloc(768 * 2);
  u16* GW = (u16*)alloc(512 * 2);
  u16* GB = (u16*)alloc(2);
  u16* OW = (u16*)alloc(1024 * 2);
  u16* OB = (u16*)alloc(2);
  u16* STMT_H   = (u16*)alloc((size_t)16 * 256 * 256 * 2);   // 2 MB  [bo][s][h]
  u16* DOCS_H   = (u16*)alloc((size_t)128 * 128 * 256 * 2);  // 8 MB  [bon][l][h]
  u16* DOC_READ = (u16*)alloc((size_t)128 * 128 * 256 * 2);  // 8 MB  [bon][l][h]
  u16* ATT      = (u16*)alloc((size_t)128 * 128 * 512 * 2);  // 16 MB [bon][l][2H]
  float* SR_R = (float*)alloc((size_t)128 * 256 * 4);
  float* DR_R = (float*)alloc((size_t)128 * 256 * 4);
  // ---- region B: 66 MB overlay, phase-disjoint lifetimes ----
  const size_t ovl = off;
  u16* REFS_B   = (u16*)(ws + ovl);                           // 8 MB   [phase 1]
  u16* STMT_IN  = (u16*)(ws + ovl + ((size_t)8 << 20));       // 2 MB   [phase 1]
  u16* XG_DOCS  = (u16*)(ws + ovl + ((size_t)16 << 20));      // 24 MB  [phase 1]
  u16* XG_STMT  = (u16*)(ws + ovl + ((size_t)41 << 20));      // 6 MB   [phase 1]
  float* MATCH  = (float*)(ws + ovl);                         // 16 MB  [phase 2]
  u16* P_ROW    = (u16*)(ws + ovl + ((size_t)16 << 20));      // 8 MB   [phase 2]
  u16* MATCH_Q  = (u16*)(ws + ovl + ((size_t)24 << 20));      // 8 MB   [phase 2]
  u16* READ_SUM = (u16*)(ws + ovl + ((size_t)50 << 20));      // 16 MB  [phase 2-3]
  u16* XG_SR    = (u16*)(ws + ovl);                           // 48 MB  [phase 3]
  float* MM     = (float*)(ws + ovl);                         // 64 MB  [phase 4]
  u16* XG_DR    = (u16*)(ws + ovl);                           // 24 MB  [phase 5]

  // 0) dtype detect
  k_detect<<<1, 64, 0, stream>>>(statement, FLAG);

  // 1) conversions / packing
  k_gather_stmt<<<4096, 256, 0, stream>>>(statement, answer, STMT_IN, FLAG);
  k_cvt<<<16384, 256, 0, stream>>>(refs, REFS_B, 4194304, FLAG);
  k_cvt<<<768, 256, 0, stream>>>(ctx_wih, CTXWIH, 196608, FLAG);
  k_cvt<<<768, 256, 0, stream>>>(sr_wih, SRWIH, 196608, FLAG);
  k_cvt<<<1536, 256, 0, stream>>>(dr_wih, DRWIH, 393216, FLAG);
  k_packh<<<384, 256, 0, stream>>>(ctx_whh, CTXWHH2, 98304, FLAG);
  k_packh<<<384, 256, 0, stream>>>(sr_whh, SRWHH2, 98304, FLAG);
  k_packh<<<384, 256, 0, stream>>>(dr_whh, DRWHH2, 98304, FLAG);
  k_cvt<<<3, 256, 0, stream>>>(ctx_bih, B_CTX_I, 768, FLAG);
  k_cvt<<<3, 256, 0, stream>>>(ctx_bhh, B_CTX_H, 768, FLAG);
  k_cvt<<<3, 256, 0, stream>>>(sr_bih, B_SR_I, 768, FLAG);
  k_cvt<<<3, 256, 0, stream>>>(sr_bhh, B_SR_H, 768, FLAG);
  k_cvt<<<3, 256, 0, stream>>>(dr_bih, B_DR_I, 768, FLAG);
  k_cvt<<<3, 256, 0, stream>>>(dr_bhh, B_DR_H, 768, FLAG);
  k_cvt<<<2, 256, 0, stream>>>(gate_w, GW, 512, FLAG);
  k_cvt<<<1, 256, 0, stream>>>(gate_b, GB, 1, FLAG);
  k_cvt<<<4, 256, 0, stream>>>(out_w, OW, 1024, FLAG);
  k_cvt<<<1, 256, 0, stream>>>(out_b, OB, 1, FLAG);

  // 2) ctx input projections: xg = X . wih^T  (M x 768, K=256)
  k_mgemm<true, false, u16, u16, u16><<<dim3(12, 64, 1), 256, 0, stream>>>(
      STMT_IN, 256, 0L, 1, CTXWIH, 256, 0L, 1, XG_STMT, 768, 0L, 256);
  k_mgemm<true, false, u16, u16, u16><<<dim3(12, 256, 1), 256, 0, stream>>>(
      REFS_B, 256, 0L, 1, CTXWIH, 256, 0L, 1, XG_DOCS, 768, 0L, 256);

  // 3) ctx GRUs, fused: stmt (16 seqs, T=256) + docs (128 seqs, T=128)
  k_rec<<<144, 768, 0, stream>>>(
      XG_STMT, CTXWHH2, B_CTX_I, B_CTX_H, STMT_H, nullptr, 16, 256,
      XG_DOCS, CTXWHH2, B_CTX_I, B_CTX_H, DOCS_H, nullptr, 128);

  // 4) match[bon][s][l] = stmt[bo] . docs[bon]^T  (M=256,N=128,K=256), fp32 out
  k_mgemm<true, false, u16, u16, float><<<dim3(2, 4, 128), 256, 0, stream>>>(
      STMT_H, 256, 65536L, 8, DOCS_H, 256, 32768L, 1, MATCH, 128, 32768L, 256);

  // 5) softmaxes from raw logits
  k_softmax_colT<<<dim3(128, 128), 256, 0, stream>>>(MATCH, MATCH_Q);
  k_softmax_row<float, u16><<<32768, 256, 0, stream>>>(MATCH, P_ROW, 128);

  // 6) read_sum[bon][s][h] = P_row . docs  (M=256,N=256,K=128), bf16 out
  k_mgemm<false, false, u16, u16, u16><<<dim3(4, 4, 128), 256, 0, stream>>>(
      P_ROW, 128, 32768L, 1, DOCS_H, 256, 32768L, 1, READ_SUM, 256, 65536L, 128);

  // 7) doc_read[bon][l][h] = MATCH_Q . stmt  (M=128,N=256,K=256) — before XG_SR overlay
  k_mgemm<false, false, u16, u16, u16><<<dim3(4, 2, 128), 256, 0, stream>>>(
      MATCH_Q, 256, 32768L, 1, STMT_H, 256, 65536L, 8, DOC_READ, 256, 32768L, 256);

  // 8) sr input projection: XG_SR = READ_SUM . sr_wih^T  (M=32768, K=256)
  k_mgemm<true, false, u16, u16, u16><<<dim3(12, 512, 1), 256, 0, stream>>>(
      READ_SUM, 256, 0L, 1, SRWIH, 256, 0L, 1, XG_SR, 768, 0L, 256);

  // 9) sr GRU (128 seqs, T=256), max-pooled
  k_rec<<<128, 768, 0, stream>>>(
      XG_SR, SRWHH2, B_SR_I, B_SR_H, nullptr, SR_R, 128, 256,
      nullptr, nullptr, nullptr, nullptr, nullptr, nullptr, 0);

  // 10) mm[bo][nl][m] = docs.docs^T + doc_read.doc_read^T  (M=N=1024,K=256 x2), fp32
  k_mgemm<true, false, u16, u16, float><<<dim3(16, 16, 16), 256, 0, stream>>>(
      DOCS_H, 256, 262144L, 1, DOCS_H, 256, 262144L, 1, MM, 1024, 1048576L, 256);
  k_mgemm<true, true, u16, u16, float><<<dim3(16, 16, 16), 256, 0, stream>>>(
      DOC_READ, 256, 262144L, 1, DOC_READ, 256, 262144L, 1, MM, 1024, 1048576L, 256);

  // 11) softmax over m, in place (fp32)
  k_softmax_row<float, float><<<16384, 256, 0, stream>>>(MM, MM, 1024);

  // 12) att[bon][l][0:256] = P . docs_flat ; [256:512] = P . doc_read_flat (bf16 out)
  k_mgemm<false, false, float, u16, u16><<<dim3(4, 16, 16), 256, 0, stream>>>(
      MM, 1024, 1048576L, 1, DOCS_H, 256, 262144L, 1, ATT, 512, 524288L, 1024);
  k_mgemm<false, false, float, u16, u16><<<dim3(4, 16, 16), 256, 0, stream>>>(
      MM, 1024, 1048576L, 1, DOC_READ, 256, 262144L, 1, ATT + 256, 512, 524288L, 1024);

  // 13) dr input projection: XG_DR = ATT . dr_wih^T  (M=16384, K=512) — MM dead
  k_mgemm<true, false, u16, u16, u16><<<dim3(12, 256, 1), 256, 0, stream>>>(
      ATT, 512, 0L, 1, DRWIH, 512, 0L, 1, XG_DR, 768, 0L, 512);

  // 14) dr GRU (128 seqs, T=128), max-pooled
  k_rec<<<128, 768, 0, stream>>>(
      XG_DR, DRWHH2, B_DR_I, B_DR_H, nullptr, DR_R, 128, 128,
      nullptr, nullptr, nullptr, nullptr, nullptr, nullptr, 0);

  // 15) gate + pool + head + softmax
  k_final<<<1, 256, 0, stream>>>(SR_R, DR_R, GW, GB, OW, OB, d_out, FLAG);
}